// Round 5
// baseline (1659.118 us; speedup 1.0000x reference)
//
#include <hip/hip_runtime.h>

// out[n] = -0.1*(deg[n]*x[n] - Ax[n]) + 0.9*hyper_res[n]
// Folded per-edge updates (31M total):
//   adj edge (s,d):        out[d] += 0.1*(x[s] - x[d])
//   hyper edge (i0,i1,i2): p = x[i1]*x[i2]; out[ij] += 0.9*(p - x[ij]^2)
//
// R2 showed device-scope atomicAdd = 31B HBM write-through per atomic (sc1,
// coherence past the 8 non-coherent per-XCD L2s) -> 968 MB -> 1.5 ms.
// R5: global_atomic_add_f32 with NO sc bits executes the RMW in the local
// XCD's L2. Correct only if each accumulator line is owned by one XCD:
// 8 private copies indexed by the *physical* XCC_ID hardware register
// (wave's actual XCD). Kernel-end dispatch release writes L2 back; the
// reduce kernel then sums the 8 copies.

#define NCOPIES 8

__device__ __forceinline__ int phys_xcd() {
    // s_getreg(HW_REG_XCC_ID): id=20, offset=0, size=4 -> imm = 20 | (3<<11)
    return __builtin_amdgcn_s_getreg(20 | (3 << 11)) & (NCOPIES - 1);
}

__device__ __forceinline__ void l2_atomic_add(float* p, float v) {
    // No sc0/sc1: RMW performed in the local XCD's L2 (no write-through to
    // the device coherence point). Valid because copy `xcc` is only ever
    // touched from XCD `xcc`.
    asm volatile("global_atomic_add_f32 %0, %1, off" :: "v"(p), "v"(v) : "memory");
}

// ---------------- zero ----------------

__global__ __launch_bounds__(256) void zero_f4_kernel(float4* __restrict__ p, long long n4) {
    long long tid = (long long)blockIdx.x * blockDim.x + threadIdx.x;
    long long stride = (long long)gridDim.x * blockDim.x;
    for (long long i = tid; i < n4; i += stride) p[i] = make_float4(0.f, 0.f, 0.f, 0.f);
}

// ---------------- scatter with XCD-local L2 atomics ----------------

__global__ __launch_bounds__(256) void scatter_xcd_kernel(
    const float* __restrict__ x,
    const int2*  __restrict__ adj,    // (n_adj, 2)
    const int*   __restrict__ hyper,  // (n_hyper, 3) flat
    float*       __restrict__ copies, // NCOPIES * stride_nodes
    int n_adj, int n_hyper, int stride_nodes)
{
    float* __restrict__ my = copies + (long long)phys_xcd() * stride_nodes;

    const long long tid    = (long long)blockIdx.x * blockDim.x + threadIdx.x;
    const long long stride = (long long)gridDim.x * blockDim.x;

    // ---- adjacency edges: one L2-local atomic per edge ----
    for (long long i = tid; i < n_adj; i += stride) {
        int2 e = adj[i];
        l2_atomic_add(&my[e.y], 0.1f * (x[e.x] - x[e.y]));
    }

    // ---- hyper edges: three L2-local atomics per edge ----
    for (long long i = tid; i < n_hyper; i += stride) {
        int i0 = hyper[3*i], i1 = hyper[3*i+1], i2 = hyper[3*i+2];
        float x0 = x[i0], x1 = x[i1], x2 = x[i2];
        float p = x1 * x2;
        l2_atomic_add(&my[i0], 0.9f * (p - x0*x0));
        l2_atomic_add(&my[i1], 0.9f * (p - x1*x1));
        l2_atomic_add(&my[i2], 0.9f * (p - x2*x2));
    }
}

// ---------------- reduce the 8 copies ----------------

__global__ __launch_bounds__(256) void reduce_copies_kernel(
    const float4* __restrict__ copies, float4* __restrict__ out,
    int n4_out, int stride4)
{
    long long tid    = (long long)blockIdx.x * blockDim.x + threadIdx.x;
    long long stride = (long long)gridDim.x * blockDim.x;
    for (long long i = tid; i < n4_out; i += stride) {
        float4 s = make_float4(0.f, 0.f, 0.f, 0.f);
        #pragma unroll
        for (int k = 0; k < NCOPIES; ++k) {
            float4 v = copies[(long long)k * stride4 + i];
            s.x += v.x; s.y += v.y; s.z += v.z; s.w += v.w;
        }
        out[i] = s;
    }
}

// ---------------- fallback (device-scope atomics, R2 path) ----------------

__global__ __launch_bounds__(256) void fused_scatter_kernel(
    const float* __restrict__ x, const int2* __restrict__ adj,
    const int* __restrict__ hyper, float* __restrict__ out,
    int n_adj, int n_hyper)
{
    const long long tid = (long long)blockIdx.x * blockDim.x + threadIdx.x;
    const long long stride = (long long)gridDim.x * blockDim.x;
    for (long long i = tid; i < n_adj; i += stride) {
        int2 e = adj[i];
        atomicAdd(&out[e.y], 0.1f * (x[e.x] - x[e.y]));
    }
    for (long long i = tid; i < n_hyper; i += stride) {
        int i0 = hyper[3*i], i1 = hyper[3*i+1], i2 = hyper[3*i+2];
        float x0 = x[i0], x1 = x[i1], x2 = x[i2];
        float p = x1 * x2;
        atomicAdd(&out[i0], 0.9f * (p - x0*x0));
        atomicAdd(&out[i1], 0.9f * (p - x1*x1));
        atomicAdd(&out[i2], 0.9f * (p - x2*x2));
    }
}

// ---------------- launcher ----------------

extern "C" void kernel_launch(void* const* d_in, const int* in_sizes, int n_in,
                              void* d_out, int out_size, void* d_ws, size_t ws_size,
                              hipStream_t stream) {
    const float* x     = (const float*)d_in[0];
    const int*   hyper = (const int*)d_in[2];
    const int2*  adj   = (const int2*)d_in[3];
    float*       out   = (float*)d_out;

    const int n_nodes = in_sizes[0];
    const int n_hyper = in_sizes[2] / 3;
    const int n_adj   = in_sizes[3] / 2;

    const int stride_nodes = (n_nodes + 255) & ~255;     // float4-aligned copy stride
    const size_t need = (size_t)NCOPIES * stride_nodes * sizeof(float);

    if (ws_size >= need) {
        float* copies = (float*)d_ws;
        const long long n4_total = (long long)NCOPIES * stride_nodes / 4;

        zero_f4_kernel<<<1024, 256, 0, stream>>>((float4*)copies, n4_total);

        scatter_xcd_kernel<<<2048, 256, 0, stream>>>(x, adj, hyper, copies,
                                                     n_adj, n_hyper, stride_nodes);

        reduce_copies_kernel<<<512, 256, 0, stream>>>((const float4*)copies,
                                                      (float4*)out,
                                                      n_nodes / 4, stride_nodes / 4);
        // n_nodes = 500000 is divisible by 4; guard the remainder anyway
        if (n_nodes & 3) {
            // (not hit for this problem; kept for generality via fallback)
        }
    } else {
        zero_f4_kernel<<<512, 256, 0, stream>>>((float4*)out, n_nodes / 4);
        fused_scatter_kernel<<<2048, 256, 0, stream>>>(x, adj, hyper, out, n_adj, n_hyper);
    }
}

// Round 6
// 1136.274 us; speedup vs baseline: 1.4601x; 1.4601x over previous
//
#include <hip/hip_runtime.h>
#include <hip/hip_fp16.h>

// out[n] = -0.1*(deg[n]*x[n] - Ax[n]) + 0.9*hyper_res[n]
// Folded per-edge updates (31M total):
//   adj edge (s,d):        out[d] += 0.1*(x[s] - x[d])
//   hyper edge (i0,i1,i2): p = x[i1]*x[i2]; out[ij] += 0.9*(p - x[ij]^2)
//
// R5 post-mortem: global atomics are memory-side write-through (~31B/op,
// ~20G/s) regardless of scope -> binning is the right skeleton.
// R4's binning was serialized by 8-way same-address returning LDS atomics on
// 62 block-shared counters + flush barriers + 900K global cursor atomics.
// R6: per-WAVE counters (conflict-free), deterministic per-(wave,bucket)
// global record segments (no cursors, no staging, no barriers). Scattered
// 4B record stores combine in write-back L2 (grid capped so active lines
// fit per-XCD L2). Rare segment overflow -> fp32 device atomic (correct).

#define W_BUCKET   8192
#define W_SHIFT    13
#define NB_MAX     62
#define A_BLOCKS   384
#define A_THREADS  512
#define NWAVES     (A_THREADS / 64)        // 8
#define NWGID      (A_BLOCKS * NWAVES)     // 3072 wave-segments per bucket
#define CAP_SEG    224                     // mean fill 163, +4.8 sigma
#define B_PB       16                      // phase-B blocks per bucket
#define SEG_PER_BLK (NWGID / B_PB)         // 192

// ---------------- zero ----------------

__global__ __launch_bounds__(256) void zero_f4_kernel(float4* __restrict__ p, long long n4) {
    long long tid = (long long)blockIdx.x * blockDim.x + threadIdx.x;
    long long stride = (long long)gridDim.x * blockDim.x;
    for (long long i = tid; i < n4; i += stride) p[i] = make_float4(0.f, 0.f, 0.f, 0.f);
}

// ---------------- phase A: barrier-free binning ----------------

__device__ __forceinline__ void append_rec(int dst, float v, int* __restrict__ curw,
                                           unsigned int* __restrict__ g_records,
                                           float* __restrict__ g_direct, int wgid) {
    int b = dst >> W_SHIFT;
    int pos = atomicAdd(&curw[b], 1);       // wave-private counter: ~conflict-free
    if (pos < CAP_SEG) {
        unsigned int rec = ((unsigned int)(dst & (W_BUCKET - 1)) << 16)
                         | (unsigned int)__half_as_ushort(__float2half(v));
        g_records[((long long)b * NWGID + wgid) * CAP_SEG + pos] = rec;
    } else {
        atomicAdd(&g_direct[dst], v);       // rare overflow: full-precision direct
    }
}

__global__ __launch_bounds__(A_THREADS) void binning_kernel(
    const float* __restrict__ x,
    const int2*  __restrict__ adj, int n_adj,
    const int*   __restrict__ hyper, int n_hyper,
    float*        __restrict__ g_direct,
    unsigned int* __restrict__ g_records,
    int*          __restrict__ g_counts,
    int nb)
{
    __shared__ int cur[NWAVES * 64];

    const int tid  = threadIdx.x;
    const int wave = tid >> 6;
    const int lane = tid & 63;
    int* curw = &cur[wave * 64];

    curw[lane] = 0;     // per-wave private; DS ops from a wave are in-order -> no barrier

    const int wgid = blockIdx.x * NWAVES + wave;
    const long long tg     = (long long)blockIdx.x * A_THREADS + tid;
    const long long stride = (long long)A_BLOCKS * A_THREADS;

    // ---- adjacency edges: one record per edge ----
    for (long long i = tg; i < n_adj; i += stride) {
        int2 e = adj[i];
        append_rec(e.y, 0.1f * (x[e.x] - x[e.y]), curw, g_records, g_direct, wgid);
    }

    // ---- hyper edges: three records per edge ----
    for (long long i = tg; i < n_hyper; i += stride) {
        int i0 = hyper[3*i], i1 = hyper[3*i+1], i2 = hyper[3*i+2];
        float x0 = x[i0], x1 = x[i1], x2 = x[i2];
        float p = x1 * x2;
        append_rec(i0, 0.9f * (p - x0*x0), curw, g_records, g_direct, wgid);
        append_rec(i1, 0.9f * (p - x1*x1), curw, g_records, g_direct, wgid);
        append_rec(i2, 0.9f * (p - x2*x2), curw, g_records, g_direct, wgid);
    }

    // publish counts (wave-private, so no cross-wave sync needed)
    if (lane < nb) {
        int c = min(curw[lane], CAP_SEG);
        g_counts[lane * NWGID + wgid] = c;
    }
}

// ---------------- phase B: per-bucket LDS accumulation ----------------

__device__ __forceinline__ void acc_one(float* acc, unsigned int rec) {
    float v = __half2float(__ushort_as_half((unsigned short)(rec & 0xffffu)));
    atomicAdd(&acc[rec >> 16], v);            // LDS atomic, no return
}

__global__ __launch_bounds__(512) void accumulate_kernel(
    const unsigned int* __restrict__ g_records,
    const int*  __restrict__ g_counts,
    float* __restrict__ partials)
{
    __shared__ float acc[W_BUCKET];            // 32 KB
    const int b = blockIdx.x / B_PB;
    const int j = blockIdx.x % B_PB;

    for (int i = threadIdx.x; i < W_BUCKET; i += blockDim.x) acc[i] = 0.f;
    __syncthreads();

    const int wave = threadIdx.x >> 6;
    const int lane = threadIdx.x & 63;
    const int seg0 = j * SEG_PER_BLK;

    for (int s = seg0 + wave; s < seg0 + SEG_PER_BLK; s += (512 / 64)) {
        int cnt = g_counts[b * NWGID + s];
        const uint4* rec4 = (const uint4*)(g_records + ((long long)b * NWGID + s) * CAP_SEG);
        int n4 = (cnt + 3) >> 2;
        for (int i4 = lane; i4 < n4; i4 += 64) {
            uint4 r = rec4[i4];
            int base = i4 << 2;
            if (base + 3 < cnt) {
                acc_one(acc, r.x); acc_one(acc, r.y);
                acc_one(acc, r.z); acc_one(acc, r.w);
            } else {
                if (base + 0 < cnt) acc_one(acc, r.x);
                if (base + 1 < cnt) acc_one(acc, r.y);
                if (base + 2 < cnt) acc_one(acc, r.z);
                if (base + 3 < cnt) acc_one(acc, r.w);
            }
        }
    }
    __syncthreads();

    float* p = partials + (long long)blockIdx.x * W_BUCKET;
    for (int i = threadIdx.x; i < W_BUCKET; i += blockDim.x) p[i] = acc[i];
}

// ---------------- phase C: reduce partials + direct into out ----------------

__global__ __launch_bounds__(256) void finalize_kernel(
    const float* __restrict__ partials,
    const float* __restrict__ g_direct,
    float* __restrict__ out, int n_nodes)
{
    int tid = blockIdx.x * blockDim.x + threadIdx.x;
    int stride = gridDim.x * blockDim.x;
    for (int n = tid; n < n_nodes; n += stride) {
        int b = n >> W_SHIFT, l = n & (W_BUCKET - 1);
        float s = g_direct[n];
        const float* p = partials + ((long long)b * B_PB) * W_BUCKET + l;
        #pragma unroll
        for (int j = 0; j < B_PB; ++j) s += p[(long long)j * W_BUCKET];
        out[n] = s;
    }
}

// ---------------- fallback (device-scope atomics, R2 path) ----------------

__global__ __launch_bounds__(256) void fused_scatter_kernel(
    const float* __restrict__ x, const int2* __restrict__ adj,
    const int* __restrict__ hyper, float* __restrict__ out,
    int n_adj, int n_hyper)
{
    const long long tid = (long long)blockIdx.x * blockDim.x + threadIdx.x;
    const long long stride = (long long)gridDim.x * blockDim.x;
    for (long long i = tid; i < n_adj; i += stride) {
        int2 e = adj[i];
        atomicAdd(&out[e.y], 0.1f * (x[e.x] - x[e.y]));
    }
    for (long long i = tid; i < n_hyper; i += stride) {
        int i0 = hyper[3*i], i1 = hyper[3*i+1], i2 = hyper[3*i+2];
        float x0 = x[i0], x1 = x[i1], x2 = x[i2];
        float p = x1 * x2;
        atomicAdd(&out[i0], 0.9f * (p - x0*x0));
        atomicAdd(&out[i1], 0.9f * (p - x1*x1));
        atomicAdd(&out[i2], 0.9f * (p - x2*x2));
    }
}

// ---------------- launcher ----------------

extern "C" void kernel_launch(void* const* d_in, const int* in_sizes, int n_in,
                              void* d_out, int out_size, void* d_ws, size_t ws_size,
                              hipStream_t stream) {
    const float* x     = (const float*)d_in[0];
    const int*   hyper = (const int*)d_in[2];
    const int2*  adj   = (const int2*)d_in[3];
    float*       out   = (float*)d_out;

    const int n_nodes = in_sizes[0];
    const int n_hyper = in_sizes[2] / 3;
    const int n_adj   = in_sizes[3] / 2;
    const int nb      = (n_nodes + W_BUCKET - 1) / W_BUCKET;

    // ws layout (byte offsets)
    const size_t off_direct = 0;                                   // n_nodes f32
    size_t off_counts = (size_t)n_nodes * 4;
    off_counts = (off_counts + 255) & ~(size_t)255;
    const size_t counts_bytes = (size_t)NB_MAX * NWGID * 4;
    size_t off_rec = off_counts + counts_bytes;
    off_rec = (off_rec + 1023) & ~(size_t)1023;
    const size_t rec_bytes = (size_t)NB_MAX * NWGID * CAP_SEG * 4; // ~171 MB
    size_t off_part = off_rec + rec_bytes;
    off_part = (off_part + 255) & ~(size_t)255;
    const size_t part_bytes = (size_t)NB_MAX * B_PB * W_BUCKET * 4;
    const size_t need = off_part + part_bytes;                     // ~206 MB

    if (nb <= NB_MAX && (n_nodes & 3) == 0 && ws_size >= need) {
        float*        g_direct  = (float*)        ((char*)d_ws + off_direct);
        int*          g_counts  = (int*)          ((char*)d_ws + off_counts);
        unsigned int* g_records = (unsigned int*) ((char*)d_ws + off_rec);
        float*        partials  = (float*)        ((char*)d_ws + off_part);

        // zero only g_direct (counts always fully written; records read < count)
        zero_f4_kernel<<<256, 256, 0, stream>>>((float4*)g_direct, n_nodes / 4);

        binning_kernel<<<A_BLOCKS, A_THREADS, 0, stream>>>(
            x, adj, n_adj, hyper, n_hyper, g_direct, g_records, g_counts, nb);

        accumulate_kernel<<<nb * B_PB, 512, 0, stream>>>(g_records, g_counts, partials);

        finalize_kernel<<<1024, 256, 0, stream>>>(partials, g_direct, out, n_nodes);
    } else {
        zero_f4_kernel<<<512, 256, 0, stream>>>((float4*)out, n_nodes / 4);
        fused_scatter_kernel<<<2048, 256, 0, stream>>>(x, adj, hyper, out, n_adj, n_hyper);
    }
}

// Round 7
// 582.327 us; speedup vs baseline: 2.8491x; 1.9513x over previous
//
#include <hip/hip_runtime.h>
#include <hip/hip_fp16.h>

// out[n] = -0.1*(deg[n]*x[n] - Ax[n]) + 0.9*hyper_res[n]
// Folded per-edge updates (31M total):
//   adj edge (s,d):        out[d] += 0.1*(x[s] - x[d])
//   hyper edge (i0,i1,i2): p = x[i1]*x[i2]; out[ij] += 0.9*(p - x[ij]^2)
//
// Measured so far:
//   - global atomics: ~31B HBM write-through each, any scope (R2/R5).
//   - scattered 4B stores: ~20B write-through each, no L2 combining (R6).
//   - ONLY coalesced staged flushes write cheap (R4: 137 MB for 124 MB of
//     records). So: R4 skeleton (block LDS stage + cursor flush).
// R7 changes vs R4:
//   - ILP-4 appends (int4 edge loads, 4 outstanding ds_add_rtn) to break the
//     one-record-per-lane latency chain (R4 binning was latency-bound).
//   - unsafeAtomicAdd -> native ds_add_f32 in accumulate (suspected CAS loop),
//     8 records/lane/iter for MLP.

#define W_BUCKET   8192
#define W_SHIFT    13
#define NB_MAX     62
#define S_STAGE    128             // staged records per bucket per tile
#define A_THREADS  512
#define A_BLOCKS   1024
#define ADJ_TILE   4096            // edges/tile  -> mean 66 rec/bucket
#define HYP_TILE   1536            // edges/tile  -> 4608 rec, mean 74/bucket
#define B_PB       16              // phase-B blocks per bucket
#define CAP_BUCKET 540672          // 66*8192; mean fill ~508K + slack

// ---------------- fallback path ----------------

__global__ __launch_bounds__(256) void zero_f4_kernel(float4* __restrict__ p, long long n4) {
    long long tid = (long long)blockIdx.x * blockDim.x + threadIdx.x;
    long long stride = (long long)gridDim.x * blockDim.x;
    for (long long i = tid; i < n4; i += stride) p[i] = make_float4(0.f, 0.f, 0.f, 0.f);
}

__global__ __launch_bounds__(256) void fused_scatter_kernel(
    const float* __restrict__ x, const int2* __restrict__ adj,
    const int* __restrict__ hyper, float* __restrict__ out,
    int n_adj, int n_hyper)
{
    const long long tid = (long long)blockIdx.x * blockDim.x + threadIdx.x;
    const long long stride = (long long)gridDim.x * blockDim.x;
    for (long long i = tid; i < n_adj; i += stride) {
        int2 e = adj[i];
        atomicAdd(&out[e.y], 0.1f * (x[e.x] - x[e.y]));
    }
    for (long long i = tid; i < n_hyper; i += stride) {
        int i0 = hyper[3*i], i1 = hyper[3*i+1], i2 = hyper[3*i+2];
        float x0 = x[i0], x1 = x[i1], x2 = x[i2];
        float p = x1 * x2;
        atomicAdd(&out[i0], 0.9f * (p - x0*x0));
        atomicAdd(&out[i1], 0.9f * (p - x1*x1));
        atomicAdd(&out[i2], 0.9f * (p - x2*x2));
    }
}

// ---------------- phase 0 ----------------

__global__ __launch_bounds__(256) void zero_int_kernel(int* __restrict__ p, int n) {
    int tid = blockIdx.x * blockDim.x + threadIdx.x;
    int stride = gridDim.x * blockDim.x;
    for (int i = tid; i < n; i += stride) p[i] = 0;
}

// ---------------- phase A: staged binning with ILP-4 appends ----------------

__device__ __forceinline__ unsigned int enc_rec(int dst, float v) {
    return ((unsigned int)(dst & (W_BUCKET - 1)) << 16)
         | (unsigned int)__half_as_ushort(__float2half(v));
}

__device__ __forceinline__ void stage_put(int b, int pos, int dst, float v,
                                          unsigned int* stage,
                                          float* __restrict__ g_direct) {
    if (pos < S_STAGE) stage[b * S_STAGE + pos] = enc_rec(dst, v);
    else atomicAdd(&g_direct[dst], v);       // rare stage overflow: fp32 direct
}

__device__ __forceinline__ void flush_stage(int nb, int* cur, int* basev, int* cnts,
                                            unsigned int* stage,
                                            int* __restrict__ g_cursor,
                                            unsigned int* __restrict__ g_records,
                                            float* __restrict__ g_direct,
                                            int wave, int lane, int nwaves) {
    __syncthreads();                          // appends of this tile done
    if (wave == 0 && lane < nb) {
        int c = min(cur[lane], S_STAGE);
        cur[lane] = 0;
        int base = 0;
        if (c > 0) base = atomicAdd(&g_cursor[lane], c);
        basev[lane] = base;
        cnts[lane]  = c;
    }
    __syncthreads();                          // basev/cnts ready, cur reset visible
    for (int b = wave; b < nb; b += nwaves) {
        int c = cnts[b];
        long long base = basev[b];
        for (int r = lane; r < c; r += 64) {
            long long idx = base + r;
            unsigned int rec = stage[b * S_STAGE + r];
            if (idx < CAP_BUCKET) {
                g_records[(long long)b * CAP_BUCKET + idx] = rec;
            } else {  // capacity overflow: direct global (decode fp16)
                float v = __half2float(__ushort_as_half((unsigned short)(rec & 0xffffu)));
                atomicAdd(&g_direct[b * W_BUCKET + (int)(rec >> 16)], v);
            }
        }
    }
    __syncthreads();                          // stage free for next tile
}

__global__ __launch_bounds__(A_THREADS) void binning_kernel(
    const float* __restrict__ x,
    const int*  __restrict__ adj_raw, int n_adj,    // (n_adj,2) flat ints
    const int*  __restrict__ hyper, int n_hyper,    // (n_hyper,3) flat ints
    int* __restrict__ g_cursor,
    float* __restrict__ g_direct,
    unsigned int* __restrict__ g_records,
    int nb)
{
    __shared__ unsigned int stage[NB_MAX * S_STAGE];   // 31.75 KB
    __shared__ int cur[NB_MAX];
    __shared__ int basev[NB_MAX];
    __shared__ int cnts[NB_MAX];

    const int tid = threadIdx.x;
    const int wave = tid >> 6;
    const int lane = tid & 63;
    const int nwaves = A_THREADS >> 6;

    for (int b = tid; b < nb; b += A_THREADS) cur[b] = 0;
    __syncthreads();

    // ---- adjacency edges (ILP-4: two aligned int4 = 4 edges) ----
    {
        long long per_blk = ((n_adj + A_BLOCKS - 1) / A_BLOCKS + 7) & ~7LL;
        long long a0 = (long long)blockIdx.x * per_blk;
        long long a1 = min((long long)n_adj, a0 + per_blk);
        for (long long t0 = a0; t0 < a1; t0 += ADJ_TILE) {
            long long t1 = min(a1, t0 + ADJ_TILE);
            for (long long g = t0 + (long long)tid * 4; g < t1; g += (long long)A_THREADS * 4) {
                if (g + 4 <= t1) {
                    const int4* p4 = (const int4*)(adj_raw + 2 * g);  // g even -> 16B aligned
                    int4 ea = p4[0], eb = p4[1];
                    float v0 = 0.1f * (x[ea.x] - x[ea.y]);
                    float v1 = 0.1f * (x[ea.z] - x[ea.w]);
                    float v2 = 0.1f * (x[eb.x] - x[eb.y]);
                    float v3 = 0.1f * (x[eb.z] - x[eb.w]);
                    int b0 = ea.y >> W_SHIFT, b1 = ea.w >> W_SHIFT;
                    int b2 = eb.y >> W_SHIFT, b3 = eb.w >> W_SHIFT;
                    int p0 = atomicAdd(&cur[b0], 1);
                    int p1 = atomicAdd(&cur[b1], 1);
                    int p2 = atomicAdd(&cur[b2], 1);
                    int p3 = atomicAdd(&cur[b3], 1);
                    stage_put(b0, p0, ea.y, v0, stage, g_direct);
                    stage_put(b1, p1, ea.w, v1, stage, g_direct);
                    stage_put(b2, p2, eb.y, v2, stage, g_direct);
                    stage_put(b3, p3, eb.w, v3, stage, g_direct);
                } else {
                    for (long long i = g; i < t1; ++i) {
                        int s = adj_raw[2*i], d = adj_raw[2*i+1];
                        float v = 0.1f * (x[s] - x[d]);
                        int b = d >> W_SHIFT;
                        int p = atomicAdd(&cur[b], 1);
                        stage_put(b, p, d, v, stage, g_direct);
                    }
                }
            }
            flush_stage(nb, cur, basev, cnts, stage, g_cursor, g_records, g_direct,
                        wave, lane, nwaves);
        }
    }

    // ---- hyper edges (ILP-4: three aligned int4 = 4 edges = 12 records) ----
    {
        long long per_blk = ((n_hyper + A_BLOCKS - 1) / A_BLOCKS + 7) & ~7LL;
        long long h0 = (long long)blockIdx.x * per_blk;
        long long h1 = min((long long)n_hyper, h0 + per_blk);
        for (long long t0 = h0; t0 < h1; t0 += HYP_TILE) {
            long long t1 = min(h1, t0 + HYP_TILE);
            for (long long g = t0 + (long long)tid * 4; g < t1; g += (long long)A_THREADS * 4) {
                if (g + 4 <= t1) {
                    const int4* p4 = (const int4*)(hyper + 3 * g);    // g%4==0 -> aligned
                    int4 w0 = p4[0], w1 = p4[1], w2 = p4[2];
                    // edges: (w0.x,w0.y,w0.z) (w0.w,w1.x,w1.y) (w1.z,w1.w,w2.x) (w2.y,w2.z,w2.w)
                    int idx[12] = { w0.x, w0.y, w0.z,  w0.w, w1.x, w1.y,
                                    w1.z, w1.w, w2.x,  w2.y, w2.z, w2.w };
                    float xv[12];
                    #pragma unroll
                    for (int k = 0; k < 12; ++k) xv[k] = x[idx[k]];
                    #pragma unroll
                    for (int e = 0; e < 4; ++e) {
                        float xa = xv[3*e], xb = xv[3*e+1], xc = xv[3*e+2];
                        float pr = xb * xc;
                        int ia = idx[3*e], ib = idx[3*e+1], ic = idx[3*e+2];
                        int ba = ia >> W_SHIFT, bb = ib >> W_SHIFT, bc = ic >> W_SHIFT;
                        int pa = atomicAdd(&cur[ba], 1);
                        int pb = atomicAdd(&cur[bb], 1);
                        int pc = atomicAdd(&cur[bc], 1);
                        stage_put(ba, pa, ia, 0.9f * (pr - xa*xa), stage, g_direct);
                        stage_put(bb, pb, ib, 0.9f * (pr - xb*xb), stage, g_direct);
                        stage_put(bc, pc, ic, 0.9f * (pr - xc*xc), stage, g_direct);
                    }
                } else {
                    for (long long i = g; i < t1; ++i) {
                        int i0 = hyper[3*i], i1 = hyper[3*i+1], i2 = hyper[3*i+2];
                        float x0 = x[i0], x1 = x[i1], x2 = x[i2];
                        float pr = x1 * x2;
                        int b0 = i0 >> W_SHIFT, b1 = i1 >> W_SHIFT, b2 = i2 >> W_SHIFT;
                        int p0 = atomicAdd(&cur[b0], 1);
                        int p1 = atomicAdd(&cur[b1], 1);
                        int p2 = atomicAdd(&cur[b2], 1);
                        stage_put(b0, p0, i0, 0.9f * (pr - x0*x0), stage, g_direct);
                        stage_put(b1, p1, i1, 0.9f * (pr - x1*x1), stage, g_direct);
                        stage_put(b2, p2, i2, 0.9f * (pr - x2*x2), stage, g_direct);
                    }
                }
            }
            flush_stage(nb, cur, basev, cnts, stage, g_cursor, g_records, g_direct,
                        wave, lane, nwaves);
        }
    }
}

// ---------------- phase B: per-bucket LDS accumulation ----------------

__device__ __forceinline__ void acc_one(float* acc, unsigned int rec) {
    float v = __half2float(__ushort_as_half((unsigned short)(rec & 0xffffu)));
    unsafeAtomicAdd(&acc[rec >> 16], v);      // native ds_add_f32, no CAS loop
}

__global__ __launch_bounds__(512) void accumulate_kernel(
    const unsigned int* __restrict__ g_records,
    const int*  __restrict__ g_cursor,
    float* __restrict__ partials)
{
    __shared__ float acc[W_BUCKET];            // 32 KB
    const int b = blockIdx.x / B_PB;
    const int j = blockIdx.x % B_PB;

    for (int i = threadIdx.x; i < W_BUCKET; i += blockDim.x) acc[i] = 0.f;
    __syncthreads();

    long long cnt = min(g_cursor[b], CAP_BUCKET);
    long long g8  = (cnt + 7) >> 3;            // 8-record groups
    long long s8  = g8 * j / B_PB;
    long long e8  = g8 * (j + 1) / B_PB;
    const uint4* rec4 = (const uint4*)(g_records + (long long)b * CAP_BUCKET);

    for (long long i8 = s8 + threadIdx.x; i8 < e8; i8 += blockDim.x) {
        uint4 r0 = rec4[2*i8], r1 = rec4[2*i8 + 1];
        long long base = i8 << 3;
        if (base + 7 < cnt) {
            acc_one(acc, r0.x); acc_one(acc, r0.y); acc_one(acc, r0.z); acc_one(acc, r0.w);
            acc_one(acc, r1.x); acc_one(acc, r1.y); acc_one(acc, r1.z); acc_one(acc, r1.w);
        } else {
            if (base + 0 < cnt) acc_one(acc, r0.x);
            if (base + 1 < cnt) acc_one(acc, r0.y);
            if (base + 2 < cnt) acc_one(acc, r0.z);
            if (base + 3 < cnt) acc_one(acc, r0.w);
            if (base + 4 < cnt) acc_one(acc, r1.x);
            if (base + 5 < cnt) acc_one(acc, r1.y);
            if (base + 6 < cnt) acc_one(acc, r1.z);
            if (base + 7 < cnt) acc_one(acc, r1.w);
        }
    }
    __syncthreads();

    float* p = partials + (long long)blockIdx.x * W_BUCKET;
    for (int i = threadIdx.x; i < W_BUCKET; i += blockDim.x) p[i] = acc[i];
}

// ---------------- phase C: reduce partials + direct into out ----------------

__global__ __launch_bounds__(256) void finalize_kernel(
    const float* __restrict__ partials,
    const float* __restrict__ g_direct,
    float* __restrict__ out, int n_nodes)
{
    int tid = blockIdx.x * blockDim.x + threadIdx.x;
    int stride = gridDim.x * blockDim.x;
    for (int n = tid; n < n_nodes; n += stride) {
        int b = n >> W_SHIFT, l = n & (W_BUCKET - 1);
        float s = g_direct[n];
        const float* p = partials + ((long long)b * B_PB) * W_BUCKET + l;
        #pragma unroll
        for (int j = 0; j < B_PB; ++j) s += p[(long long)j * W_BUCKET];
        out[n] = s;
    }
}

// ---------------- launcher ----------------

extern "C" void kernel_launch(void* const* d_in, const int* in_sizes, int n_in,
                              void* d_out, int out_size, void* d_ws, size_t ws_size,
                              hipStream_t stream) {
    const float* x     = (const float*)d_in[0];
    const int*   hyper = (const int*)d_in[2];
    const int*   adj   = (const int*)d_in[3];
    float*       out   = (float*)d_out;

    const int n_nodes = in_sizes[0];
    const int n_hyper = in_sizes[2] / 3;
    const int n_adj   = in_sizes[3] / 2;
    const int nb      = (n_nodes + W_BUCKET - 1) / W_BUCKET;

    // ws layout (byte offsets)
    const size_t off_cursor = 0;                                   // 64 ints
    const size_t off_direct = 256;                                 // n_nodes f32
    size_t off_rec = off_direct + (size_t)n_nodes * 4;
    off_rec = (off_rec + 255) & ~(size_t)255;
    const size_t rec_bytes  = (size_t)NB_MAX * CAP_BUCKET * 4;     // ~134 MB
    size_t off_part = off_rec + rec_bytes;
    off_part = (off_part + 255) & ~(size_t)255;
    const size_t part_bytes = (size_t)NB_MAX * B_PB * W_BUCKET * 4;
    const size_t need = off_part + part_bytes;

    if (nb <= NB_MAX && (n_nodes & 3) == 0 && ws_size >= need) {
        int*          g_cursor  = (int*)          ((char*)d_ws + off_cursor);
        float*        g_direct  = (float*)        ((char*)d_ws + off_direct);
        unsigned int* g_records = (unsigned int*) ((char*)d_ws + off_rec);
        float*        partials  = (float*)        ((char*)d_ws + off_part);

        // zero cursors + direct accumulator (contiguous prefix of ws)
        zero_int_kernel<<<256, 256, 0, stream>>>((int*)d_ws, (int)(off_rec / 4));

        binning_kernel<<<A_BLOCKS, A_THREADS, 0, stream>>>(
            x, adj, n_adj, hyper, n_hyper, g_cursor, g_direct, g_records, nb);

        accumulate_kernel<<<nb * B_PB, 512, 0, stream>>>(g_records, g_cursor, partials);

        finalize_kernel<<<1024, 256, 0, stream>>>(partials, g_direct, out, n_nodes);
    } else {
        zero_f4_kernel<<<512, 256, 0, stream>>>((float4*)out, n_nodes / 4);
        fused_scatter_kernel<<<2048, 256, 0, stream>>>(x, (const int2*)adj, hyper, out,
                                                       n_adj, n_hyper);
    }
}

// Round 8
// 518.968 us; speedup vs baseline: 3.1970x; 1.1221x over previous
//
#include <hip/hip_runtime.h>
#include <hip/hip_fp16.h>

// out[n] = -0.1*(deg[n]*x[n] - Ax[n]) + 0.9*hyper_res[n]
// Folded per-edge updates (31M total):
//   adj edge (s,d):        out[d] += 0.1*(x[s] - x[d])
//   hyper edge (i0,i1,i2): p = x[i1]*x[i2]; out[ij] += 0.9*(p - x[ij]^2)
//
// Measured laws so far (R2..R7):
//   - global atomics: ~31B HBM write-through each, any scope.
//   - scattered sub-line stores: ~20B write-through each, no L2 combining.
//   - coalesced staged flushes are the only cheap scatter path.
//   - R7 binning is GATHER-bound: 47M diverged x[] gathers ~= 1 line txn each.
// R8: adj records carry (dst_local:13 | src:19) -> adj binning is gather-FREE;
// accumulate defers the gather (x[src] random, x[dst] from an LDS x-slice).
// Hyper unchanged (3 gathers/edge produce product + squares). 47M -> 31M gathers.

#define W_BUCKET   8192
#define W_SHIFT    13
#define NB_MAX     62
#define S_STAGE    128             // staged records per bucket per tile
#define A_THREADS  512
#define A_BLOCKS   1024
#define ADJ_TILE   4096            // edges/tile  -> mean 66 rec/bucket
#define HYP_TILE   1536            // edges/tile  -> 4608 rec, mean 74/bucket
#define B_PB       16              // phase-B blocks per bucket
#define CAP_A      262144          // adj recs/bucket: mean 258K, +8 sigma
#define CAP_H      245760          // hyp recs/bucket: mean 242K, +7.8 sigma
#define SRC_MASK   0x7FFFFu

// ---------------- fallback path ----------------

__global__ __launch_bounds__(256) void zero_f4_kernel(float4* __restrict__ p, long long n4) {
    long long tid = (long long)blockIdx.x * blockDim.x + threadIdx.x;
    long long stride = (long long)gridDim.x * blockDim.x;
    for (long long i = tid; i < n4; i += stride) p[i] = make_float4(0.f, 0.f, 0.f, 0.f);
}

__global__ __launch_bounds__(256) void fused_scatter_kernel(
    const float* __restrict__ x, const int2* __restrict__ adj,
    const int* __restrict__ hyper, float* __restrict__ out,
    int n_adj, int n_hyper)
{
    const long long tid = (long long)blockIdx.x * blockDim.x + threadIdx.x;
    const long long stride = (long long)gridDim.x * blockDim.x;
    for (long long i = tid; i < n_adj; i += stride) {
        int2 e = adj[i];
        atomicAdd(&out[e.y], 0.1f * (x[e.x] - x[e.y]));
    }
    for (long long i = tid; i < n_hyper; i += stride) {
        int i0 = hyper[3*i], i1 = hyper[3*i+1], i2 = hyper[3*i+2];
        float x0 = x[i0], x1 = x[i1], x2 = x[i2];
        float p = x1 * x2;
        atomicAdd(&out[i0], 0.9f * (p - x0*x0));
        atomicAdd(&out[i1], 0.9f * (p - x1*x1));
        atomicAdd(&out[i2], 0.9f * (p - x2*x2));
    }
}

// ---------------- phase 0 ----------------

__global__ __launch_bounds__(256) void zero_int_kernel(int* __restrict__ p, int n) {
    int tid = blockIdx.x * blockDim.x + threadIdx.x;
    int stride = gridDim.x * blockDim.x;
    for (int i = tid; i < n; i += stride) p[i] = 0;
}

// ---------------- phase A: staged binning ----------------

// flush one tile's stage to a record region. kind=0: adj recs, kind=1: hyper.
template <int KIND>
__device__ __forceinline__ void flush_stage(int nb, int* cur, int* basev, int* cnts,
                                            unsigned int* stage,
                                            int* __restrict__ g_cursor,
                                            unsigned int* __restrict__ g_records,
                                            long long cap,
                                            const float* __restrict__ x,
                                            float* __restrict__ g_direct,
                                            int wave, int lane, int nwaves) {
    __syncthreads();                          // appends of this tile done
    if (wave == 0 && lane < nb) {
        int c = min(cur[lane], S_STAGE);
        cur[lane] = 0;
        int base = 0;
        if (c > 0) base = atomicAdd(&g_cursor[lane], c);
        basev[lane] = base;
        cnts[lane]  = c;
    }
    __syncthreads();
    for (int b = wave; b < nb; b += nwaves) {
        int c = cnts[b];
        long long base = basev[b];
        for (int r = lane; r < c; r += 64) {
            long long idx = base + r;
            unsigned int rec = stage[b * S_STAGE + r];
            if (idx < cap) {
                g_records[(long long)b * cap + idx] = rec;
            } else if (KIND == 0) {           // adj capacity overflow (rare)
                int src = rec & SRC_MASK;
                int dst = b * W_BUCKET + (int)(rec >> 19);
                atomicAdd(&g_direct[dst], 0.1f * (x[src] - x[dst]));
            } else {                          // hyper capacity overflow (rare)
                float v = __half2float(__ushort_as_half((unsigned short)(rec & 0xffffu)));
                atomicAdd(&g_direct[b * W_BUCKET + (int)(rec >> 16)], v);
            }
        }
    }
    __syncthreads();                          // stage free for next tile
}

__global__ __launch_bounds__(A_THREADS) void binning_kernel(
    const float* __restrict__ x,
    const int*  __restrict__ adj_raw, int n_adj,    // (n_adj,2) flat ints
    const int*  __restrict__ hyper, int n_hyper,    // (n_hyper,3) flat ints
    int* __restrict__ cur_a, int* __restrict__ cur_h,
    float* __restrict__ g_direct,
    unsigned int* __restrict__ rec_a,
    unsigned int* __restrict__ rec_h,
    int nb)
{
    __shared__ unsigned int stage[NB_MAX * S_STAGE];   // 31.75 KB
    __shared__ int cur[NB_MAX];
    __shared__ int basev[NB_MAX];
    __shared__ int cnts[NB_MAX];

    const int tid = threadIdx.x;
    const int wave = tid >> 6;
    const int lane = tid & 63;
    const int nwaves = A_THREADS >> 6;

    for (int b = tid; b < nb; b += A_THREADS) cur[b] = 0;
    __syncthreads();

    // ---- adjacency edges: NO x access, record = (dst_local<<19)|src ----
    {
        long long per_blk = ((n_adj + A_BLOCKS - 1) / A_BLOCKS + 7) & ~7LL;
        long long a0 = (long long)blockIdx.x * per_blk;
        long long a1 = min((long long)n_adj, a0 + per_blk);
        for (long long t0 = a0; t0 < a1; t0 += ADJ_TILE) {
            long long t1 = min(a1, t0 + ADJ_TILE);
            for (long long g = t0 + (long long)tid * 4; g < t1; g += (long long)A_THREADS * 4) {
                if (g + 4 <= t1) {
                    const int4* p4 = (const int4*)(adj_raw + 2 * g);  // 16B aligned
                    int4 ea = p4[0], eb = p4[1];
                    int s0 = ea.x, d0 = ea.y,  s1 = ea.z, d1 = ea.w;
                    int s2 = eb.x, d2 = eb.y,  s3 = eb.z, d3 = eb.w;
                    int b0 = d0 >> W_SHIFT, b1 = d1 >> W_SHIFT;
                    int b2 = d2 >> W_SHIFT, b3 = d3 >> W_SHIFT;
                    int p0 = atomicAdd(&cur[b0], 1);
                    int p1 = atomicAdd(&cur[b1], 1);
                    int p2 = atomicAdd(&cur[b2], 1);
                    int p3 = atomicAdd(&cur[b3], 1);
                    if (p0 < S_STAGE) stage[b0*S_STAGE+p0] = ((unsigned)(d0 & (W_BUCKET-1)) << 19) | (unsigned)s0;
                    else atomicAdd(&g_direct[d0], 0.1f * (x[s0] - x[d0]));
                    if (p1 < S_STAGE) stage[b1*S_STAGE+p1] = ((unsigned)(d1 & (W_BUCKET-1)) << 19) | (unsigned)s1;
                    else atomicAdd(&g_direct[d1], 0.1f * (x[s1] - x[d1]));
                    if (p2 < S_STAGE) stage[b2*S_STAGE+p2] = ((unsigned)(d2 & (W_BUCKET-1)) << 19) | (unsigned)s2;
                    else atomicAdd(&g_direct[d2], 0.1f * (x[s2] - x[d2]));
                    if (p3 < S_STAGE) stage[b3*S_STAGE+p3] = ((unsigned)(d3 & (W_BUCKET-1)) << 19) | (unsigned)s3;
                    else atomicAdd(&g_direct[d3], 0.1f * (x[s3] - x[d3]));
                } else {
                    for (long long i = g; i < t1; ++i) {
                        int s = adj_raw[2*i], d = adj_raw[2*i+1];
                        int b = d >> W_SHIFT;
                        int p = atomicAdd(&cur[b], 1);
                        if (p < S_STAGE) stage[b*S_STAGE+p] = ((unsigned)(d & (W_BUCKET-1)) << 19) | (unsigned)s;
                        else atomicAdd(&g_direct[d], 0.1f * (x[s] - x[d]));
                    }
                }
            }
            flush_stage<0>(nb, cur, basev, cnts, stage, cur_a, rec_a, CAP_A,
                           x, g_direct, wave, lane, nwaves);
        }
    }

    // ---- hyper edges (ILP-4: three aligned int4 = 4 edges = 12 records) ----
    {
        long long per_blk = ((n_hyper + A_BLOCKS - 1) / A_BLOCKS + 7) & ~7LL;
        long long h0 = (long long)blockIdx.x * per_blk;
        long long h1 = min((long long)n_hyper, h0 + per_blk);
        for (long long t0 = h0; t0 < h1; t0 += HYP_TILE) {
            long long t1 = min(h1, t0 + HYP_TILE);
            for (long long g = t0 + (long long)tid * 4; g < t1; g += (long long)A_THREADS * 4) {
                if (g + 4 <= t1) {
                    const int4* p4 = (const int4*)(hyper + 3 * g);    // 16B aligned
                    int4 w0 = p4[0], w1 = p4[1], w2 = p4[2];
                    int idx[12] = { w0.x, w0.y, w0.z,  w0.w, w1.x, w1.y,
                                    w1.z, w1.w, w2.x,  w2.y, w2.z, w2.w };
                    float xv[12];
                    #pragma unroll
                    for (int k = 0; k < 12; ++k) xv[k] = x[idx[k]];
                    #pragma unroll
                    for (int e = 0; e < 4; ++e) {
                        float xa = xv[3*e], xb = xv[3*e+1], xc = xv[3*e+2];
                        float pr = xb * xc;
                        int ia = idx[3*e], ib = idx[3*e+1], ic = idx[3*e+2];
                        int ba = ia >> W_SHIFT, bb = ib >> W_SHIFT, bc = ic >> W_SHIFT;
                        int pa = atomicAdd(&cur[ba], 1);
                        int pb = atomicAdd(&cur[bb], 1);
                        int pc = atomicAdd(&cur[bc], 1);
                        float va = 0.9f * (pr - xa*xa);
                        float vb = 0.9f * (pr - xb*xb);
                        float vc = 0.9f * (pr - xc*xc);
                        if (pa < S_STAGE) stage[ba*S_STAGE+pa] = ((unsigned)(ia & (W_BUCKET-1)) << 16) | (unsigned)__half_as_ushort(__float2half(va));
                        else atomicAdd(&g_direct[ia], va);
                        if (pb < S_STAGE) stage[bb*S_STAGE+pb] = ((unsigned)(ib & (W_BUCKET-1)) << 16) | (unsigned)__half_as_ushort(__float2half(vb));
                        else atomicAdd(&g_direct[ib], vb);
                        if (pc < S_STAGE) stage[bc*S_STAGE+pc] = ((unsigned)(ic & (W_BUCKET-1)) << 16) | (unsigned)__half_as_ushort(__float2half(vc));
                        else atomicAdd(&g_direct[ic], vc);
                    }
                } else {
                    for (long long i = g; i < t1; ++i) {
                        int i0 = hyper[3*i], i1 = hyper[3*i+1], i2 = hyper[3*i+2];
                        float x0 = x[i0], x1 = x[i1], x2 = x[i2];
                        float pr = x1 * x2;
                        int b0 = i0 >> W_SHIFT, b1 = i1 >> W_SHIFT, b2 = i2 >> W_SHIFT;
                        int p0 = atomicAdd(&cur[b0], 1);
                        int p1 = atomicAdd(&cur[b1], 1);
                        int p2 = atomicAdd(&cur[b2], 1);
                        float v0 = 0.9f * (pr - x0*x0);
                        float v1 = 0.9f * (pr - x1*x1);
                        float v2 = 0.9f * (pr - x2*x2);
                        if (p0 < S_STAGE) stage[b0*S_STAGE+p0] = ((unsigned)(i0 & (W_BUCKET-1)) << 16) | (unsigned)__half_as_ushort(__float2half(v0));
                        else atomicAdd(&g_direct[i0], v0);
                        if (p1 < S_STAGE) stage[b1*S_STAGE+p1] = ((unsigned)(i1 & (W_BUCKET-1)) << 16) | (unsigned)__half_as_ushort(__float2half(v1));
                        else atomicAdd(&g_direct[i1], v1);
                        if (p2 < S_STAGE) stage[b2*S_STAGE+p2] = ((unsigned)(i2 & (W_BUCKET-1)) << 16) | (unsigned)__half_as_ushort(__float2half(v2));
                        else atomicAdd(&g_direct[i2], v2);
                    }
                }
            }
            flush_stage<1>(nb, cur, basev, cnts, stage, cur_h, rec_h, CAP_H,
                           x, g_direct, wave, lane, nwaves);
        }
    }
}

// ---------------- phase B: per-bucket LDS accumulation ----------------

__global__ __launch_bounds__(512) void accumulate_kernel(
    const float* __restrict__ x,
    const unsigned int* __restrict__ rec_a,
    const unsigned int* __restrict__ rec_h,
    const int* __restrict__ cur_a,
    const int* __restrict__ cur_h,
    float* __restrict__ partials, int n_nodes)
{
    __shared__ float  acc[W_BUCKET];           // 32 KB
    __shared__ __half xs[W_BUCKET];            // 16 KB x-slice
    const int b = blockIdx.x / B_PB;
    const int j = blockIdx.x % B_PB;
    const int base_node = b * W_BUCKET;

    for (int i = threadIdx.x; i < W_BUCKET; i += 512) {
        acc[i] = 0.f;
        int n = base_node + i;
        xs[i] = __float2half(n < n_nodes ? x[n] : 0.f);
    }
    __syncthreads();

    // ---- adj records: v = 0.1*(x[src] - xs[dst]) ----
    {
        long long cnt = min(cur_a[b], CAP_A);
        long long g8 = (cnt + 7) >> 3;
        long long s8 = g8 * j / B_PB, e8 = g8 * (j + 1) / B_PB;
        const uint4* r4 = (const uint4*)(rec_a + (long long)b * CAP_A);
        for (long long i8 = s8 + threadIdx.x; i8 < e8; i8 += 512) {
            uint4 r0 = r4[2*i8], r1 = r4[2*i8 + 1];
            long long base = i8 << 3;
            unsigned rr[8] = { r0.x, r0.y, r0.z, r0.w, r1.x, r1.y, r1.z, r1.w };
            if (base + 7 < cnt) {
                float xv[8];
                #pragma unroll
                for (int k = 0; k < 8; ++k) xv[k] = x[rr[k] & SRC_MASK];
                #pragma unroll
                for (int k = 0; k < 8; ++k) {
                    int dl = rr[k] >> 19;
                    unsafeAtomicAdd(&acc[dl], 0.1f * (xv[k] - __half2float(xs[dl])));
                }
            } else {
                #pragma unroll
                for (int k = 0; k < 8; ++k) {
                    if (base + k < cnt) {
                        int dl = rr[k] >> 19;
                        unsafeAtomicAdd(&acc[dl],
                            0.1f * (x[rr[k] & SRC_MASK] - __half2float(xs[dl])));
                    }
                }
            }
        }
    }

    // ---- hyper records: fp16 value ----
    {
        long long cnt = min(cur_h[b], CAP_H);
        long long g8 = (cnt + 7) >> 3;
        long long s8 = g8 * j / B_PB, e8 = g8 * (j + 1) / B_PB;
        const uint4* r4 = (const uint4*)(rec_h + (long long)b * CAP_H);
        for (long long i8 = s8 + threadIdx.x; i8 < e8; i8 += 512) {
            uint4 r0 = r4[2*i8], r1 = r4[2*i8 + 1];
            long long base = i8 << 3;
            unsigned rr[8] = { r0.x, r0.y, r0.z, r0.w, r1.x, r1.y, r1.z, r1.w };
            #pragma unroll
            for (int k = 0; k < 8; ++k) {
                if (base + k < cnt) {
                    float v = __half2float(__ushort_as_half((unsigned short)(rr[k] & 0xffffu)));
                    unsafeAtomicAdd(&acc[rr[k] >> 16], v);
                }
            }
        }
    }
    __syncthreads();

    float* p = partials + (long long)blockIdx.x * W_BUCKET;
    for (int i = threadIdx.x; i < W_BUCKET; i += 512) p[i] = acc[i];
}

// ---------------- phase C: reduce partials + direct into out ----------------

__global__ __launch_bounds__(256) void finalize_kernel(
    const float* __restrict__ partials,
    const float* __restrict__ g_direct,
    float* __restrict__ out, int n_nodes)
{
    int tid = blockIdx.x * blockDim.x + threadIdx.x;
    int stride = gridDim.x * blockDim.x;
    for (int n = tid; n < n_nodes; n += stride) {
        int b = n >> W_SHIFT, l = n & (W_BUCKET - 1);
        float s = g_direct[n];
        const float* p = partials + ((long long)b * B_PB) * W_BUCKET + l;
        #pragma unroll
        for (int j = 0; j < B_PB; ++j) s += p[(long long)j * W_BUCKET];
        out[n] = s;
    }
}

// ---------------- launcher ----------------

extern "C" void kernel_launch(void* const* d_in, const int* in_sizes, int n_in,
                              void* d_out, int out_size, void* d_ws, size_t ws_size,
                              hipStream_t stream) {
    const float* x     = (const float*)d_in[0];
    const int*   hyper = (const int*)d_in[2];
    const int*   adj   = (const int*)d_in[3];
    float*       out   = (float*)d_out;

    const int n_nodes = in_sizes[0];
    const int n_hyper = in_sizes[2] / 3;
    const int n_adj   = in_sizes[3] / 2;
    const int nb      = (n_nodes + W_BUCKET - 1) / W_BUCKET;

    // ws layout (byte offsets)
    const size_t off_cur    = 0;                                   // 128 ints
    const size_t off_direct = 512;                                 // n_nodes f32
    size_t off_ra = off_direct + (size_t)n_nodes * 4;
    off_ra = (off_ra + 255) & ~(size_t)255;
    const size_t ra_bytes = (size_t)NB_MAX * CAP_A * 4;            // ~65 MB
    size_t off_rh = off_ra + ra_bytes;
    const size_t rh_bytes = (size_t)NB_MAX * CAP_H * 4;            // ~61 MB
    size_t off_part = off_rh + rh_bytes;
    off_part = (off_part + 255) & ~(size_t)255;
    const size_t part_bytes = (size_t)NB_MAX * B_PB * W_BUCKET * 4;
    const size_t need = off_part + part_bytes;                     // ~161 MB

    if (nb <= NB_MAX && n_nodes <= (1 << 19) && (n_nodes & 3) == 0 && ws_size >= need) {
        int*          cur_a    = (int*)          ((char*)d_ws + off_cur);
        int*          cur_h    = (int*)          ((char*)d_ws + off_cur + 256);
        float*        g_direct = (float*)        ((char*)d_ws + off_direct);
        unsigned int* rec_a    = (unsigned int*) ((char*)d_ws + off_ra);
        unsigned int* rec_h    = (unsigned int*) ((char*)d_ws + off_rh);
        float*        partials = (float*)        ((char*)d_ws + off_part);

        // zero cursors + direct accumulator (contiguous prefix of ws)
        zero_int_kernel<<<256, 256, 0, stream>>>((int*)d_ws, (int)(off_ra / 4));

        binning_kernel<<<A_BLOCKS, A_THREADS, 0, stream>>>(
            x, adj, n_adj, hyper, n_hyper, cur_a, cur_h, g_direct, rec_a, rec_h, nb);

        accumulate_kernel<<<nb * B_PB, 512, 0, stream>>>(
            x, rec_a, rec_h, cur_a, cur_h, partials, n_nodes);

        finalize_kernel<<<1024, 256, 0, stream>>>(partials, g_direct, out, n_nodes);
    } else {
        zero_f4_kernel<<<512, 256, 0, stream>>>((float4*)out, n_nodes / 4);
        fused_scatter_kernel<<<2048, 256, 0, stream>>>(x, (const int2*)adj, hyper, out,
                                                       n_adj, n_hyper);
    }
}